// Round 13
// baseline (232.462 us; speedup 1.0000x reference)
//
#include <hip/hip_runtime.h>
#include <math.h>

#define N_TOK   65536
#define HID     1024
#define NEXP    64
#define EPSF    1e-12f
#define EPSW    4e-5f     // provable-safety window >> bf16-split error bound

typedef __attribute__((ext_vector_type(8))) short s16x8;   // 8 bf16
typedef __attribute__((ext_vector_type(4))) float f32x4;

__device__ __forceinline__ unsigned short f2bf(float f) {   // RNE f32->bf16
    unsigned u = __float_as_uint(f);
    unsigned r = u + 0x7fffu + ((u >> 16) & 1u);
    return (unsigned short)(r >> 16);
}
__device__ __forceinline__ float bf2f(unsigned short h) {
    return __uint_as_float(((unsigned)h) << 16);
}
__device__ __forceinline__ unsigned enc_key(float f) {
    unsigned u = __float_as_uint(f);
    return (u & 0x80000000u) ? ~u : (u | 0x80000000u);
}
__device__ __forceinline__ float dec_key(unsigned k) {
    unsigned u = (k & 0x80000000u) ? (k ^ 0x80000000u) : ~k;
    return __uint_as_float(u);
}

// ---------------- prep: ws[0..63] = 1/||sim col||, ws[64..127] = sigmoid(gates)
__global__ __launch_bounds__(256) void prep_kernel(const float* __restrict__ sim,
                                                   const float* __restrict__ gates,
                                                   float* __restrict__ ws) {
    __shared__ float partial[4][64];
    int e = threadIdx.x & 63;
    int q = threadIdx.x >> 6;
    float s = 0.f;
    for (int h = q * 256; h < q * 256 + 256; ++h) {
        float v = sim[h * NEXP + e];
        s += v * v;
    }
    partial[q][e] = s;
    __syncthreads();
    if (threadIdx.x < 64) {
        float ss = partial[0][e] + partial[1][e] + partial[2][e] + partial[3][e];
        ws[e] = 1.0f / fmaxf(sqrtf(ss), EPSF);
        ws[64 + e] = 1.0f / (1.0f + expf(-gates[e]));
    }
}

// ---------------- prep2: normalized W f32: wn[k*64+e] = sim[k*64+e]*invcol[e]
__global__ __launch_bounds__(256) void prep2n_kernel(const float* __restrict__ sim,
                                                     const float* __restrict__ ws_ro,
                                                     float* __restrict__ wn) {
    int idx = blockIdx.x * 256 + threadIdx.x;
    wn[idx] = sim[idx] * ws_ro[idx & 63];
}

// ---------------- prep3: B-fragment bf16 split of wn for mfma_f32_16x16x32_bf16.
// Lane l supplies B[k=(l>>4)*8+j][col=l&15]. i = ((kt*4 + nt)*64 + lane)*8 + j.
__global__ __launch_bounds__(256) void prep3_kernel(const float* __restrict__ wn,
                                                    unsigned short* __restrict__ wbh,
                                                    unsigned short* __restrict__ wbl) {
    int i = blockIdx.x * 256 + threadIdx.x;     // 0..65535
    int j    = i & 7;
    int lane = (i >> 3) & 63;
    int nt   = (i >> 9) & 3;
    int kt   = i >> 11;
    int k = kt * 32 + ((lane >> 4) & 3) * 8 + j;
    int e = nt * 16 + (lane & 15);
    float v = wn[k * NEXP + e];
    unsigned short h = f2bf(v);
    unsigned short l = f2bf(v - bf2f(h));
    wbh[i] = h; wbl[i] = l;
}

// ---------------- main kernel v13: barrier-free per-wave MFMA with DEEP
// register prefetch. v12 structure, but: B fragments prefetched depth-1 in
// registers (issued before chunk c's MFMAs), x prefetched depth-2. This is
// the clean test of the "x-stream evicts B from cache -> per-chunk B loads
// eat L3/HBM latency" theory (v11 had prefetch+barrier-drain, v12 had
// neither; both ~230us; v10's LDS-resident W avoided it entirely).
__global__ __launch_bounds__(256) void gate_v13_kernel(const float* __restrict__ x,
                                                       const float* __restrict__ wn,
                                                       const unsigned short* __restrict__ wbh,
                                                       const unsigned short* __restrict__ wbl,
                                                       const float* __restrict__ prep,
                                                       float* __restrict__ out) {
    __shared__ __align__(16) float lg[64][68];   // raw logits (dot products)
    __shared__ __align__(16) float xrow[HID];    // exact-pass row stage
    __shared__ float ss_l[64];
    __shared__ float thr_l[64];
    __shared__ int   flags_i[64];
    __shared__ float part[256];

    const int tid   = threadIdx.x;
    const int lane  = tid & 63;
    const int wv    = tid >> 6;
    const int tbase = blockIdx.x * 64;

    const int arow = lane & 15;          // A-row (token within wave tile)
    const int aoct = lane >> 4;          // k-octet 0..3
    const float* xg = x + (size_t)(tbase + wv * 16 + arow) * HID + aoct * 8;

    if (tid < 64) thr_l[tid] = prep[64 + tid];

    f32x4 acc[4];
#pragma unroll
    for (int nt = 0; nt < 4; ++nt) acc[nt] = (f32x4){0.f, 0.f, 0.f, 0.f};
    float ss = 0.f;

    const s16x8* bh_g = (const s16x8*)wbh;
    const s16x8* bl_g = (const s16x8*)wbl;

    // ---- prologue: x chunks 0,1 and B chunk 0 in registers ----
    float4 xv0 = *(const float4*)(xg);
    float4 xv1 = *(const float4*)(xg + 4);
    float4 p10 = *(const float4*)(xg + 32);
    float4 p11 = *(const float4*)(xg + 36);
    s16x8 bh[4], bl[4];
#pragma unroll
    for (int nt = 0; nt < 4; ++nt) {
        bh[nt] = bh_g[nt * 64 + lane];
        bl[nt] = bl_g[nt * 64 + lane];
    }

#pragma unroll 1
    for (int c = 0; c < 32; ++c) {
        // issue NEXT chunk's B loads first (depth-1, covered by this chunk's work)
        s16x8 nbh[4], nbl[4];
        if (c < 31) {
#pragma unroll
            for (int nt = 0; nt < 4; ++nt) {
                nbh[nt] = bh_g[((c + 1) * 4 + nt) * 64 + lane];
                nbl[nt] = bl_g[((c + 1) * 4 + nt) * 64 + lane];
            }
        }
        // issue x chunk c+2 (depth-2, covers HBM latency)
        float4 p20, p21;
        if (c < 30) {
            p20 = *(const float4*)(xg + (c + 2) * 32);
            p21 = *(const float4*)(xg + (c + 2) * 32 + 4);
        }

        // convert current x octet to bf16 hi/lo, fuse ss
        const float a[8] = { xv0.x, xv0.y, xv0.z, xv0.w, xv1.x, xv1.y, xv1.z, xv1.w };
        s16x8 ah, al;
#pragma unroll
        for (int i = 0; i < 8; ++i) {
            ss = fmaf(a[i], a[i], ss);
            unsigned short h = f2bf(a[i]);
            ah[i] = (short)h;
            al[i] = (short)f2bf(a[i] - bf2f(h));
        }
        // 3-pass bf16-split MFMA (current B, fully resident in registers)
#pragma unroll
        for (int nt = 0; nt < 4; ++nt)
            acc[nt] = __builtin_amdgcn_mfma_f32_16x16x32_bf16(al, bh[nt], acc[nt], 0, 0, 0);
#pragma unroll
        for (int nt = 0; nt < 4; ++nt)
            acc[nt] = __builtin_amdgcn_mfma_f32_16x16x32_bf16(ah, bl[nt], acc[nt], 0, 0, 0);
#pragma unroll
        for (int nt = 0; nt < 4; ++nt)
            acc[nt] = __builtin_amdgcn_mfma_f32_16x16x32_bf16(ah, bh[nt], acc[nt], 0, 0, 0);

        // rotate pipeline registers
#pragma unroll
        for (int nt = 0; nt < 4; ++nt) { bh[nt] = nbh[nt]; bl[nt] = nbl[nt]; }
        xv0 = p10; xv1 = p11;
        p10 = p20; p11 = p21;
    }

    // ss: reduce over the 4 k-octet groups (lanes differing in bits 4,5)
    ss += __shfl_xor(ss, 16);
    ss += __shfl_xor(ss, 32);
    if (lane < 16) ss_l[wv * 16 + lane] = ss;

    // dump logits: D layout col=lane&15 (expert), row=(lane>>4)*4+r (token)
#pragma unroll
    for (int nt = 0; nt < 4; ++nt)
#pragma unroll
        for (int r = 0; r < 4; ++r)
            lg[wv * 16 + aoct * 4 + r][nt * 16 + arow] = acc[nt][r];
    __syncthreads();

    // ---- approx epilogue (v11/v12-verified): wave wv -> tokens wv*16..+15 ----
    const int tg = lane >> 3;
    const int eg = lane & 7;
    const int e0 = eg * 8;
    const size_t out_pre  = (size_t)N_TOK * NEXP;
    const size_t out_mask = 2 * (size_t)N_TOK * NEXP;

#pragma unroll
    for (int j = 0; j < 2; ++j) {
        const int tl = wv * 16 + tg * 2 + j;
        const int t  = tbase + tl;
        const float inv = 1.0f / fmaxf(sqrtf(ss_l[tl]), EPSF);

        float logit[8], pre[8];
        int active[8];
        int myact = 0;
#pragma unroll
        for (int i = 0; i < 8; ++i) {
            logit[i] = lg[tl][e0 + i] * inv;
            pre[i]   = logit[i] - thr_l[e0 + i];
            active[i] = pre[i] > 0.f;
            myact += active[i];
        }
        *(float4*)&out[out_pre + (size_t)t * NEXP + e0]     = make_float4(pre[0], pre[1], pre[2], pre[3]);
        *(float4*)&out[out_pre + (size_t)t * NEXP + e0 + 4] = make_float4(pre[4], pre[5], pre[6], pre[7]);

        int rowact = myact;
        rowact += __shfl_xor(rowact, 1, 8);
        rowact += __shfl_xor(rowact, 2, 8);
        rowact += __shfl_xor(rowact, 4, 8);

        int flag;
        if (rowact > 0) {
            float mn = 1e30f;
#pragma unroll
            for (int i = 0; i < 8; ++i) mn = fminf(mn, fabsf(pre[i]));
            mn = fminf(mn, __shfl_xor(mn, 1, 8));
            mn = fminf(mn, __shfl_xor(mn, 2, 8));
            mn = fminf(mn, __shfl_xor(mn, 4, 8));
            flag = (mn <= EPSW);
            if (!flag) {
                float gated[8], probs[8], mask[8];
#pragma unroll
                for (int i = 0; i < 8; ++i) gated[i] = fmaxf(pre[i], 0.f);
                float m = -INFINITY;
#pragma unroll
                for (int i = 0; i < 8; ++i) m = fmaxf(m, active[i] ? gated[i] : -INFINITY);
                m = fmaxf(m, __shfl_xor(m, 1, 8));
                m = fmaxf(m, __shfl_xor(m, 2, 8));
                m = fmaxf(m, __shfl_xor(m, 4, 8));
                float s = 0.f;
#pragma unroll
                for (int i = 0; i < 8; ++i) {
                    float ev = active[i] ? expf(gated[i] - m) : 0.f;
                    probs[i] = ev; s += ev;
                }
                s += __shfl_xor(s, 1, 8);
                s += __shfl_xor(s, 2, 8);
                s += __shfl_xor(s, 4, 8);
                float rs = 1.0f / s;
#pragma unroll
                for (int i = 0; i < 8; ++i) { probs[i] *= rs; mask[i] = active[i] ? 1.f : 0.f; }
                size_t row = (size_t)t * NEXP + e0;
                *(float4*)&out[row]                = make_float4(probs[0], probs[1], probs[2], probs[3]);
                *(float4*)&out[row + 4]            = make_float4(probs[4], probs[5], probs[6], probs[7]);
                *(float4*)&out[out_mask + row]     = make_float4(mask[0], mask[1], mask[2], mask[3]);
                *(float4*)&out[out_mask + row + 4] = make_float4(mask[4], mask[5], mask[6], mask[7]);
            }
        } else {
            unsigned key[8];
#pragma unroll
            for (int i = 0; i < 8; ++i) key[i] = enc_key(logit[i]);
            unsigned cand = 0u;
            for (int bit = 31; bit >= 0; --bit) {
                unsigned test = cand | (1u << bit);
                int c = 0;
#pragma unroll
                for (int i = 0; i < 8; ++i) c += (key[i] >= test);
                c += __shfl_xor(c, 1, 8);
                c += __shfl_xor(c, 2, 8);
                c += __shfl_xor(c, 4, 8);
                if (c >= 32) cand = test;
            }
            const float val32 = dec_key(cand);
            int nhi = 0, nlo = 0, nam = 0;
#pragma unroll
            for (int i = 0; i < 8; ++i) {
                nhi += logit[i] > val32 + EPSW;
                nlo += logit[i] > val32 - EPSW;
                nam += pre[i] > -EPSW;
            }
            nhi += __shfl_xor(nhi, 1, 8); nhi += __shfl_xor(nhi, 2, 8); nhi += __shfl_xor(nhi, 4, 8);
            nlo += __shfl_xor(nlo, 1, 8); nlo += __shfl_xor(nlo, 2, 8); nlo += __shfl_xor(nlo, 4, 8);
            nam += __shfl_xor(nam, 1, 8); nam += __shfl_xor(nam, 2, 8); nam += __shfl_xor(nam, 4, 8);
            flag = !(nhi == 31 && nlo == 32) || (nam > 0);
            if (!flag) {
                float probs[8], mask[8];
#pragma unroll
                for (int i = 0; i < 8; ++i) {
                    int sel = logit[i] > val32 - EPSW;   // provably the exact top-32 set
                    mask[i]  = sel ? 1.f : 0.f;
                    probs[i] = sel ? 0.03125f : 0.f;
                }
                size_t row = (size_t)t * NEXP + e0;
                *(float4*)&out[row]                = make_float4(probs[0], probs[1], probs[2], probs[3]);
                *(float4*)&out[row + 4]            = make_float4(probs[4], probs[5], probs[6], probs[7]);
                *(float4*)&out[out_mask + row]     = make_float4(mask[0], mask[1], mask[2], mask[3]);
                *(float4*)&out[out_mask + row + 4] = make_float4(mask[4], mask[5], mask[6], mask[7]);
            }
        }
        if (eg == 0) flags_i[tl] = flag;
    }
    __syncthreads();

    // ---- exact pass for flagged rows (block-cooperative, f32) ----
    for (int tf = 0; tf < 64; ++tf) {
        if (flags_i[tf] == 0) continue;
        {
            float4 v = *(const float4*)&x[(size_t)(tbase + tf) * HID + tid * 4];
            *(float4*)&xrow[tid * 4] = v;
        }
        __syncthreads();
        const int e = tid & 63;
        const int q = tid >> 6;
        const float* wp = wn + (size_t)q * 256 * NEXP + e;
        const float* xr = xrow + q * 256;
        float dot = 0.f;
#pragma unroll 8
        for (int k2 = 0; k2 < 256; ++k2)
            dot = fmaf(xr[k2], wp[(size_t)k2 * NEXP], dot);
        part[q * 64 + e] = dot;
        __syncthreads();
        if (tid < 64) {
            const float inv = 1.0f / fmaxf(sqrtf(ss_l[tf]), EPSF);
            const float lgv = ((part[e] + part[64 + e]) + (part[128 + e] + part[192 + e])) * inv;
            const float pr = lgv - thr_l[e];
            unsigned long long act = __ballot(pr > 0.f);
            float probs, mask;
            if (act) {
                float g = fmaxf(pr, 0.f);
                float mv = (pr > 0.f) ? g : -INFINITY;
#pragma unroll
                for (int d = 1; d < 64; d <<= 1) mv = fmaxf(mv, __shfl_xor(mv, d));
                float ex = (pr > 0.f) ? expf(g - mv) : 0.f;
                float s = ex;
#pragma unroll
                for (int d = 1; d < 64; d <<= 1) s += __shfl_xor(s, d);
                probs = ex / s;
                mask  = (pr > 0.f) ? 1.f : 0.f;
            } else {
                unsigned key = enc_key(lgv);
                unsigned cand = 0u;
                for (int bit = 31; bit >= 0; --bit) {
                    unsigned test = cand | (1u << bit);
                    int c = __popcll(__ballot(key >= test));
                    if (c >= 32) cand = test;
                }
                int need = 32 - __popcll(__ballot(key > cand));
                unsigned long long em = __ballot(key == cand);
                unsigned long long mlt = e ? (~0ull >> (64 - e)) : 0ull;
                int below = __popcll(em & mlt);
                int sel = (key > cand) || ((key == cand) && (below < need));
                probs = sel ? 0.03125f : 0.f;
                mask  = sel ? 1.f : 0.f;
            }
            size_t row = (size_t)(tbase + tf) * NEXP;
            out[row + e] = probs;
            out[out_mask + row + e] = mask;
        }
        __syncthreads();
    }
}

// ---------------- v10 (round-10 kernel, fallback) ----------------
__global__ __launch_bounds__(256) void gate_v10_kernel(const float* __restrict__ x,
                                                       const float* __restrict__ wn,
                                                       const float* __restrict__ prep,
                                                       float* __restrict__ out) {
    __shared__ __align__(16) float smem[8704];
    float* ss_part = smem + 8448;
    const int tid  = threadIdx.x;
    const int lane = tid & 63;
    const int wv   = tid >> 6;
    const int tg   = lane >> 3;
    const int eg   = lane & 7;
    const int e0   = eg * 8;
    const int tbase = blockIdx.x * 64;
    const int kbase = wv * 256;
    float* xsw = smem + wv * 2112;
    const float4* xq4 = (const float4*)(x + (size_t)(tbase + lane) * HID + kbase);
    float acc[8][8];
#pragma unroll
    for (int t = 0; t < 8; ++t)
#pragma unroll
        for (int e = 0; e < 8; ++e) acc[t][e] = 0.f;
    float ss = 0.f;
    {
        float4 f0 = xq4[0], f1 = xq4[1];
        const float4* wq4 = (const float4*)(wn + (size_t)kbase * NEXP) + lane * 2;
        float4 w0 = wq4[0], w1 = wq4[1];
        const float a[8] = { f0.x, f0.y, f0.z, f0.w, f1.x, f1.y, f1.z, f1.w };
#pragma unroll
        for (int i = 0; i < 8; ++i) { ss = fmaf(a[i], a[i], ss); xsw[i * 68 + lane] = a[i]; }
        *(float4*)&xsw[1088 + lane * 8]     = w0;
        *(float4*)&xsw[1088 + lane * 8 + 4] = w1;
    }
#define FMA8x8(XA, XB, WA, WB)                                              \
    do {                                                                    \
        const float xv_[8] = { XA.x, XA.y, XA.z, XA.w, XB.x, XB.y, XB.z, XB.w }; \
        const float wv_[8] = { WA.x, WA.y, WA.z, WA.w, WB.x, WB.y, WB.z, WB.w }; \
        _Pragma("unroll")                                                   \
        for (int t_ = 0; t_ < 8; ++t_)                                      \
            _Pragma("unroll")                                               \
            for (int e_ = 0; e_ < 8; ++e_)                                  \
                acc[t_][e_] = fmaf(xv_[t_], wv_[e_], acc[t_][e_]);          \
    } while (0)
#pragma unroll 1
    for (int c = 0; c < 32; ++c) {
        float4 sx0, sx1, sw0, sw1;
        if (c < 31) {
            sx0 = xq4[(c + 1) * 2];
            sx1 = xq4[(c + 1) * 2 + 1];
            const float4* wq4 = (const float4*)(wn + (size_t)(kbase + (c + 1) * 8) * NEXP) + lane * 2;
            sw0 = wq4[0]; sw1 = wq4[1];
        }
        const float* xb = xsw + (c & 1) * 544;
        const float* wb = xsw + 1088 + (c & 1) * 512;
#pragma unroll
        for (int k = 0; k < 8; ++k) {
            const float4 xa = *(const float4*)&xb[k * 68 + tg * 8];
            const float4 xc = *(const float4*)&xb[k * 68 + tg * 8 + 4];
            const float4 wa = *(const float4*)&wb[k * 64 + e0];
            const float4 wc = *(const float4*)&wb[k * 64 + e0 + 4];
            FMA8x8(xa, xc, wa, wc);
        }
        if (c < 31) {
            float* xn = xsw + ((c + 1) & 1) * 544;
            float* wl = xsw + 1088 + ((c + 1) & 1) * 512;
            const float a[8] = { sx0.x, sx0.y, sx0.z, sx0.w, sx1.x, sx1.y, sx1.z, sx1.w };
#pragma unroll
            for (int i = 0; i < 8; ++i) { ss = fmaf(a[i], a[i], ss); xn[i * 68 + lane] = a[i]; }
            *(float4*)&wl[lane * 8]     = sw0;
            *(float4*)&wl[lane * 8 + 4] = sw1;
        }
    }
#undef FMA8x8
    ss_part[wv * 64 + lane] = ss;
    __syncthreads();
    if (wv < 2) {
        float* reg = smem + wv * 4224;
#pragma unroll
        for (int j = 0; j < 8; ++j) {
            float* p = &reg[(tg * 8 + j) * 65 + e0];
            *(float4*)(p)     = make_float4(acc[j][0], acc[j][1], acc[j][2], acc[j][3]);
            *(float4*)(p + 4) = make_float4(acc[j][4], acc[j][5], acc[j][6], acc[j][7]);
        }
    }
    __syncthreads();
    if (wv >= 2) {
        float* reg = smem + (wv - 2) * 4224;
#pragma unroll
        for (int j = 0; j < 8; ++j) {
            float* p = &reg[(tg * 8 + j) * 65 + e0];
            float4 p0 = *(const float4*)(p);
            float4 p1 = *(const float4*)(p + 4);
            p0.x += acc[j][0]; p0.y += acc[j][1]; p0.z += acc[j][2]; p0.w += acc[j][3];
            p1.x += acc[j][4]; p1.y += acc[j][5]; p1.z += acc[j][6]; p1.w += acc[j][7];
            *(float4*)(p) = p0; *(float4*)(p + 4) = p1;
        }
    }
    __syncthreads();
    float thr[8];
#pragma unroll
    for (int i = 0; i < 8; ++i) thr[i] = prep[64 + e0 + i];
    const size_t out_pre  = (size_t)N_TOK * NEXP;
    const size_t out_mask = 2 * (size_t)N_TOK * NEXP;
    const float* regA = smem;
    const float* regB = smem + 4224;
#pragma unroll
    for (int j = 0; j < 2; ++j) {
        const int tl = wv * 16 + tg * 2 + j;
        const int t  = tbase + tl;
        const float sst = (ss_part[tl] + ss_part[64 + tl]) + (ss_part[128 + tl] + ss_part[192 + tl]);
        const float inv = 1.0f / fmaxf(sqrtf(sst), EPSF);
        float4 aA0 = *(const float4*)&regA[tl * 65 + e0];
        float4 aA1 = *(const float4*)&regA[tl * 65 + e0 + 4];
        float4 aB0 = *(const float4*)&regB[tl * 65 + e0];
        float4 aB1 = *(const float4*)&regB[tl * 65 + e0 + 4];
        float logit[8] = { (aA0.x + aB0.x) * inv, (aA0.y + aB0.y) * inv,
                           (aA0.z + aB0.z) * inv, (aA0.w + aB0.w) * inv,
                           (aA1.x + aB1.x) * inv, (aA1.y + aB1.y) * inv,
                           (aA1.z + aB1.z) * inv, (aA1.w + aB1.w) * inv };
        float pre[8], gated[8];
        int active[8];
        int myact = 0;
#pragma unroll
        for (int i = 0; i < 8; ++i) {
            pre[i]   = logit[i] - thr[i];
            gated[i] = fmaxf(pre[i], 0.f);
            active[i] = pre[i] > 0.f;
            myact += active[i];
        }
        int rowact = myact;
        rowact += __shfl_xor(rowact, 1, 8);
        rowact += __shfl_xor(rowact, 2, 8);
        rowact += __shfl_xor(rowact, 4, 8);
        float probs[8], mask[8];
        if (rowact > 0) {
            float m = -INFINITY;
#pragma unroll
            for (int i = 0; i < 8; ++i) m = fmaxf(m, active[i] ? gated[i] : -INFINITY);
            m = fmaxf(m, __shfl_xor(m, 1, 8));
            m = fmaxf(m, __shfl_xor(m, 2, 8));
            m = fmaxf(m, __shfl_xor(m, 4, 8));
            float s = 0.f;
#pragma unroll
            for (int i = 0; i < 8; ++i) { float ev = active[i] ? expf(gated[i] - m) : 0.f; probs[i] = ev; s += ev; }
            s += __shfl_xor(s, 1, 8);
            s += __shfl_xor(s, 2, 8);
            s += __shfl_xor(s, 4, 8);
            float rs = 1.0f / s;
#pragma unroll
            for (int i = 0; i < 8; ++i) { probs[i] *= rs; mask[i] = active[i] ? 1.f : 0.f; }
        } else {
            unsigned key[8];
#pragma unroll
            for (int i = 0; i < 8; ++i) key[i] = enc_key(logit[i]);
            unsigned cand = 0u;
            for (int bit = 31; bit >= 0; --bit) {
                unsigned test = cand | (1u << bit);
                int c = 0;
#pragma unroll
                for (int i = 0; i < 8; ++i) c += (key[i] >= test);
                c += __shfl_xor(c, 1, 8);
                c += __shfl_xor(c, 2, 8);
                c += __shfl_xor(c, 4, 8);
                if (c >= 32) cand = test;
            }
            int cgt = 0;
#pragma unroll
            for (int i = 0; i < 8; ++i) cgt += (key[i] > cand);
            cgt += __shfl_xor(cgt, 1, 8);
            cgt += __shfl_xor(cgt, 2, 8);
            cgt += __shfl_xor(cgt, 4, 8);
            int need_eq = 32 - cgt;
            int eqc = 0;
#pragma unroll
            for (int i = 0; i < 8; ++i) eqc += (key[i] == cand);
            int scan = eqc, tmp;
            tmp = __shfl_up(scan, 1, 8); if (eg >= 1) scan += tmp;
            tmp = __shfl_up(scan, 2, 8); if (eg >= 2) scan += tmp;
            tmp = __shfl_up(scan, 4, 8); if (eg >= 4) scan += tmp;
            int run = scan - eqc;
#pragma unroll
            for (int i = 0; i < 8; ++i) {
                int sel = (key[i] > cand) || ((key[i] == cand) && (run < need_eq));
                run += (key[i] == cand);
                mask[i]  = sel ? 1.f : 0.f;
                probs[i] = sel ? 0.03125f : 0.f;
            }
        }
        const size_t row = (size_t)t * NEXP + e0;
        *(float4*)&out[row]                = make_float4(probs[0], probs[1], probs[2], probs[3]);
        *(float4*)&out[row + 4]            = make_float4(probs[4], probs[5], probs[6], probs[7]);
        *(float4*)&out[out_pre + row]      = make_float4(pre[0], pre[1], pre[2], pre[3]);
        *(float4*)&out[out_pre + row + 4]  = make_float4(pre[4], pre[5], pre[6], pre[7]);
        *(float4*)&out[out_mask + row]     = make_float4(mask[0], mask[1], mask[2], mask[3]);
        *(float4*)&out[out_mask + row + 4] = make_float4(mask[4], mask[5], mask[6], mask[7]);
    }
}

extern "C" void kernel_launch(void* const* d_in, const int* in_sizes, int n_in,
                              void* d_out, int out_size, void* d_ws, size_t ws_size,
                              hipStream_t stream) {
    (void)in_sizes; (void)n_in; (void)out_size;
    const float* x     = (const float*)d_in[0];
    const float* sim   = (const float*)d_in[1];
    const float* gates = (const float*)d_in[2];
    float* out = (float*)d_out;
    float* ws  = (float*)d_ws;

    hipLaunchKernelGGL(prep_kernel, dim3(1), dim3(256), 0, stream, sim, gates, ws);

    const size_t need_v10 = 512 + (size_t)HID * NEXP * sizeof(float);
    const size_t need_v13 = need_v10 + 2 * (size_t)HID * NEXP * sizeof(short);
    if (ws_size >= need_v13) {
        float* wn = ws + 128;
        unsigned short* wbh = (unsigned short*)((char*)ws + 512 + (size_t)HID * NEXP * 4);
        unsigned short* wbl = wbh + (size_t)HID * NEXP;
        hipLaunchKernelGGL(prep2n_kernel, dim3(HID * NEXP / 256), dim3(256), 0, stream,
                           sim, ws, wn);
        hipLaunchKernelGGL(prep3_kernel, dim3(HID * NEXP / 256), dim3(256), 0, stream,
                           wn, wbh, wbl);
        hipLaunchKernelGGL(gate_v13_kernel, dim3(N_TOK / 64), dim3(256), 0, stream,
                           x, wn, wbh, wbl, ws, out);
    } else {
        float* wn = ws + 128;
        hipLaunchKernelGGL(prep2n_kernel, dim3(HID * NEXP / 256), dim3(256), 0, stream,
                           sim, ws, wn);
        hipLaunchKernelGGL(gate_v10_kernel, dim3(N_TOK / 64), dim3(256), 0, stream,
                           x, wn, ws, out);
    }
}

// Round 14
// 181.265 us; speedup vs baseline: 1.2824x; 1.2824x over previous
//
#include <hip/hip_runtime.h>
#include <math.h>

#define N_TOK   65536
#define HID     1024
#define NEXP    64
#define EPSF    1e-12f
#define EPSW    4e-5f     // provable-safety window >> bf16-split error bound

typedef __attribute__((ext_vector_type(8))) short s16x8;   // 8 bf16
typedef __attribute__((ext_vector_type(4))) float f32x4;

__device__ __forceinline__ unsigned short f2bf(float f) {   // RNE f32->bf16
    unsigned u = __float_as_uint(f);
    unsigned r = u + 0x7fffu + ((u >> 16) & 1u);
    return (unsigned short)(r >> 16);
}
__device__ __forceinline__ float bf2f(unsigned short h) {
    return __uint_as_float(((unsigned)h) << 16);
}
__device__ __forceinline__ unsigned enc_key(float f) {
    unsigned u = __float_as_uint(f);
    return (u & 0x80000000u) ? ~u : (u | 0x80000000u);
}
__device__ __forceinline__ float dec_key(unsigned k) {
    unsigned u = (k & 0x80000000u) ? (k ^ 0x80000000u) : ~k;
    return __uint_as_float(u);
}

// ---------------- prep: ws[0..63] = 1/||sim col||, ws[64..127] = sigmoid(gates)
__global__ __launch_bounds__(256) void prep_kernel(const float* __restrict__ sim,
                                                   const float* __restrict__ gates,
                                                   float* __restrict__ ws) {
    __shared__ float partial[4][64];
    int e = threadIdx.x & 63;
    int q = threadIdx.x >> 6;
    float s = 0.f;
    for (int h = q * 256; h < q * 256 + 256; ++h) {
        float v = sim[h * NEXP + e];
        s += v * v;
    }
    partial[q][e] = s;
    __syncthreads();
    if (threadIdx.x < 64) {
        float ss = partial[0][e] + partial[1][e] + partial[2][e] + partial[3][e];
        ws[e] = 1.0f / fmaxf(sqrtf(ss), EPSF);
        ws[64 + e] = 1.0f / (1.0f + expf(-gates[e]));
    }
}

// ---------------- prep2: normalized W f32: wn[k*64+e] = sim[k*64+e]*invcol[e]
__global__ __launch_bounds__(256) void prep2n_kernel(const float* __restrict__ sim,
                                                     const float* __restrict__ ws_ro,
                                                     float* __restrict__ wn) {
    int idx = blockIdx.x * 256 + threadIdx.x;
    wn[idx] = sim[idx] * ws_ro[idx & 63];
}

// ---------------- prep3: B-fragment bf16 split of wn for mfma_f32_16x16x32_bf16.
// Lane l supplies B[k=(l>>4)*8+j][col=l&15]. i = ((kt*4 + nt)*64 + lane)*8 + j.
__global__ __launch_bounds__(256) void prep3_kernel(const float* __restrict__ wn,
                                                    unsigned short* __restrict__ wbh,
                                                    unsigned short* __restrict__ wbl) {
    int i = blockIdx.x * 256 + threadIdx.x;     // 0..65535
    int j    = i & 7;
    int lane = (i >> 3) & 63;
    int nt   = (i >> 9) & 3;
    int kt   = i >> 11;
    int k = kt * 32 + ((lane >> 4) & 3) * 8 + j;
    int e = nt * 16 + (lane & 15);
    float v = wn[k * NEXP + e];
    unsigned short h = f2bf(v);
    unsigned short l = f2bf(v - bf2f(h));
    wbh[i] = h; wbl[i] = l;
}

// ---------------- main kernel v14: v11 structure + B-fragments ALSO staged in
// LDS (read from global ONCE per block, not once per wave). Diagnosis: v11/v12/
// v13 all ~230us because each wave streamed the full 256KB B array through L3
// (1GB total, L2 thrashed by the x stream). v14 drops B traffic 4x to v10's
// level while keeping MFMA compute and 12x lower LDS traffic than v10.
__global__ __launch_bounds__(256) void gate_v14_kernel(const float* __restrict__ x,
                                                       const float* __restrict__ wn,
                                                       const unsigned short* __restrict__ wbh,
                                                       const unsigned short* __restrict__ wbl,
                                                       const float* __restrict__ prep,
                                                       float* __restrict__ out) {
    // float offsets:
    //  [0,4352)    A-frags (Ah 0..2080, Al 2080..4160); logits [64][68] overlay
    //  [4352,6400) Bh frags (2 buf x 256 slots x 16B)
    //  [6400,8448) Bl frags
    //  epilogue overlays on B region: xrow at 4352 (1024), part at 5376 (256),
    //              flags at 5632 (64 ints)
    //  [8448,8704) ss_part[4][64]   [8704,8768) thr_l
    __shared__ __align__(16) float smem[8768];
    unsigned short* AhU = (unsigned short*)smem;
    unsigned short* AlU = (unsigned short*)(smem + 2080);
    unsigned short* BhU = (unsigned short*)(smem + 4352);
    unsigned short* BlU = (unsigned short*)(smem + 6400);
    float* xrow    = smem + 4352;
    float* part    = smem + 5376;
    int*   flags_i = (int*)(smem + 5632);
    float* ss_part = smem + 8448;
    float* thr_l   = smem + 8704;

    const int tid   = threadIdx.x;
    const int lane  = tid & 63;
    const int wv    = tid >> 6;            // wave = expert n-tile
    const int tbase = blockIdx.x * 64;

    // staging identity: thread stages token t_st, k-octet q_st
    const int t_st = tid & 63;
    const int q_st = tid >> 6;
    const int fl   = (t_st & 15) + 16 * q_st;   // fragment lane it produces
    const int mt   = t_st >> 4;                 // m-tile of its token
    const float* xrow_g = x + (size_t)(tbase + t_st) * HID;

    if (tid < 64) thr_l[tid] = prep[64 + tid];

    f32x4 acc[4];
#pragma unroll
    for (int m = 0; m < 4; ++m) acc[m] = (f32x4){0.f, 0.f, 0.f, 0.f};
    float ss = 0.f;

    const s16x8* bh_g = (const s16x8*)wbh;
    const s16x8* bl_g = (const s16x8*)wbl;

    // ---- prologue: stage A chunk 0 + B chunk 0 ----
    {
        float4 v0 = *(const float4*)(xrow_g + q_st * 8);
        float4 v1 = *(const float4*)(xrow_g + q_st * 8 + 4);
        s16x8 b0h = bh_g[tid];
        s16x8 b0l = bl_g[tid];
        const float a[8] = { v0.x, v0.y, v0.z, v0.w, v1.x, v1.y, v1.z, v1.w };
        s16x8 hv, lv;
#pragma unroll
        for (int i = 0; i < 8; ++i) {
            ss = fmaf(a[i], a[i], ss);
            unsigned short h = f2bf(a[i]);
            hv[i] = (short)h;
            lv[i] = (short)f2bf(a[i] - bf2f(h));
        }
        int slot = mt * 65 + fl;               // buf 0
        *(s16x8*)&AhU[slot * 8] = hv;
        *(s16x8*)&AlU[slot * 8] = lv;
        *(s16x8*)&BhU[tid * 8] = b0h;          // buf 0 slot tid
        *(s16x8*)&BlU[tid * 8] = b0l;
    }
    __syncthreads();

#pragma unroll 1
    for (int c = 0; c < 32; ++c) {
        const int buf = c & 1;
        // issue next chunk's global loads early (covered by this chunk's work)
        float4 nv0, nv1;
        s16x8 nBh, nBl;
        if (c < 31) {
            nv0 = *(const float4*)(xrow_g + (c + 1) * 32 + q_st * 8);
            nv1 = *(const float4*)(xrow_g + (c + 1) * 32 + q_st * 8 + 4);
            nBh = bh_g[(c + 1) * 256 + tid];
            nBl = bl_g[(c + 1) * 256 + tid];
        }

        // compute: A-frags (4 m-tiles) + this wave's B frags, all from LDS
        s16x8 ah[4], al[4];
#pragma unroll
        for (int m = 0; m < 4; ++m) {
            int base = ((buf << 2) + m) * 65 * 8 + lane * 8;
            ah[m] = *(const s16x8*)&AhU[base];
            al[m] = *(const s16x8*)&AlU[base];
        }
        s16x8 bhf = *(const s16x8*)&BhU[(buf * 256 + wv * 64 + lane) * 8];
        s16x8 blf = *(const s16x8*)&BlU[(buf * 256 + wv * 64 + lane) * 8];
#pragma unroll
        for (int m = 0; m < 4; ++m)
            acc[m] = __builtin_amdgcn_mfma_f32_16x16x32_bf16(al[m], bhf, acc[m], 0, 0, 0);
#pragma unroll
        for (int m = 0; m < 4; ++m)
            acc[m] = __builtin_amdgcn_mfma_f32_16x16x32_bf16(ah[m], blf, acc[m], 0, 0, 0);
#pragma unroll
        for (int m = 0; m < 4; ++m)
            acc[m] = __builtin_amdgcn_mfma_f32_16x16x32_bf16(ah[m], bhf, acc[m], 0, 0, 0);

        // stage chunk c+1 into the other buffers
        if (c < 31) {
            const float a[8] = { nv0.x, nv0.y, nv0.z, nv0.w, nv1.x, nv1.y, nv1.z, nv1.w };
            s16x8 hv, lv;
#pragma unroll
            for (int i = 0; i < 8; ++i) {
                ss = fmaf(a[i], a[i], ss);
                unsigned short h = f2bf(a[i]);
                hv[i] = (short)h;
                lv[i] = (short)f2bf(a[i] - bf2f(h));
            }
            int slot = (((buf ^ 1) << 2) + mt) * 65 + fl;
            *(s16x8*)&AhU[slot * 8] = hv;
            *(s16x8*)&AlU[slot * 8] = lv;
            *(s16x8*)&BhU[((buf ^ 1) * 256 + tid) * 8] = nBh;
            *(s16x8*)&BlU[((buf ^ 1) * 256 + tid) * 8] = nBl;
        }
        __syncthreads();
    }

    // ---- ss partials + logits dump (A region dead; overlay) ----
    ss_part[q_st * 64 + t_st] = ss;
    {
        float* lg = smem;   // logits [64][68]
#pragma unroll
        for (int m = 0; m < 4; ++m) {
#pragma unroll
            for (int r = 0; r < 4; ++r) {
                int tok = m * 16 + (lane >> 4) * 4 + r;
                int e   = wv * 16 + (lane & 15);
                lg[tok * 68 + e] = acc[m][r];
            }
        }
    }
    __syncthreads();

    // ---- approx epilogue (v11/v12-hardware-verified) ----
    const int tg = lane >> 3;
    const int eg = lane & 7;
    const int e0 = eg * 8;
    const size_t out_pre  = (size_t)N_TOK * NEXP;
    const size_t out_mask = 2 * (size_t)N_TOK * NEXP;

#pragma unroll
    for (int j = 0; j < 2; ++j) {
        const int tl = wv * 16 + tg * 2 + j;
        const int t  = tbase + tl;
        const float sst = (ss_part[tl] + ss_part[64 + tl])
                        + (ss_part[128 + tl] + ss_part[192 + tl]);
        const float inv = 1.0f / fmaxf(sqrtf(sst), EPSF);

        float logit[8], pre[8];
        int active[8];
        int myact = 0;
#pragma unroll
        for (int i = 0; i < 8; ++i) {
            logit[i] = smem[tl * 68 + e0 + i] * inv;
            pre[i]   = logit[i] - thr_l[e0 + i];
            active[i] = pre[i] > 0.f;
            myact += active[i];
        }
        *(float4*)&out[out_pre + (size_t)t * NEXP + e0]     = make_float4(pre[0], pre[1], pre[2], pre[3]);
        *(float4*)&out[out_pre + (size_t)t * NEXP + e0 + 4] = make_float4(pre[4], pre[5], pre[6], pre[7]);

        int rowact = myact;
        rowact += __shfl_xor(rowact, 1, 8);
        rowact += __shfl_xor(rowact, 2, 8);
        rowact += __shfl_xor(rowact, 4, 8);

        int flag;
        if (rowact > 0) {
            float mn = 1e30f;
#pragma unroll
            for (int i = 0; i < 8; ++i) mn = fminf(mn, fabsf(pre[i]));
            mn = fminf(mn, __shfl_xor(mn, 1, 8));
            mn = fminf(mn, __shfl_xor(mn, 2, 8));
            mn = fminf(mn, __shfl_xor(mn, 4, 8));
            flag = (mn <= EPSW);
            if (!flag) {
                float gated[8], probs[8], mask[8];
#pragma unroll
                for (int i = 0; i < 8; ++i) gated[i] = fmaxf(pre[i], 0.f);
                float m = -INFINITY;
#pragma unroll
                for (int i = 0; i < 8; ++i) m = fmaxf(m, active[i] ? gated[i] : -INFINITY);
                m = fmaxf(m, __shfl_xor(m, 1, 8));
                m = fmaxf(m, __shfl_xor(m, 2, 8));
                m = fmaxf(m, __shfl_xor(m, 4, 8));
                float s = 0.f;
#pragma unroll
                for (int i = 0; i < 8; ++i) {
                    float ev = active[i] ? expf(gated[i] - m) : 0.f;
                    probs[i] = ev; s += ev;
                }
                s += __shfl_xor(s, 1, 8);
                s += __shfl_xor(s, 2, 8);
                s += __shfl_xor(s, 4, 8);
                float rs = 1.0f / s;
#pragma unroll
                for (int i = 0; i < 8; ++i) { probs[i] *= rs; mask[i] = active[i] ? 1.f : 0.f; }
                size_t row = (size_t)t * NEXP + e0;
                *(float4*)&out[row]                = make_float4(probs[0], probs[1], probs[2], probs[3]);
                *(float4*)&out[row + 4]            = make_float4(probs[4], probs[5], probs[6], probs[7]);
                *(float4*)&out[out_mask + row]     = make_float4(mask[0], mask[1], mask[2], mask[3]);
                *(float4*)&out[out_mask + row + 4] = make_float4(mask[4], mask[5], mask[6], mask[7]);
            }
        } else {
            unsigned key[8];
#pragma unroll
            for (int i = 0; i < 8; ++i) key[i] = enc_key(logit[i]);
            unsigned cand = 0u;
            for (int bit = 31; bit >= 0; --bit) {
                unsigned test = cand | (1u << bit);
                int c = 0;
#pragma unroll
                for (int i = 0; i < 8; ++i) c += (key[i] >= test);
                c += __shfl_xor(c, 1, 8);
                c += __shfl_xor(c, 2, 8);
                c += __shfl_xor(c, 4, 8);
                if (c >= 32) cand = test;
            }
            const float val32 = dec_key(cand);
            int nhi = 0, nlo = 0, nam = 0;
#pragma unroll
            for (int i = 0; i < 8; ++i) {
                nhi += logit[i] > val32 + EPSW;
                nlo += logit[i] > val32 - EPSW;
                nam += pre[i] > -EPSW;
            }
            nhi += __shfl_xor(nhi, 1, 8); nhi += __shfl_xor(nhi, 2, 8); nhi += __shfl_xor(nhi, 4, 8);
            nlo += __shfl_xor(nlo, 1, 8); nlo += __shfl_xor(nlo, 2, 8); nlo += __shfl_xor(nlo, 4, 8);
            nam += __shfl_xor(nam, 1, 8); nam += __shfl_xor(nam, 2, 8); nam += __shfl_xor(nam, 4, 8);
            flag = !(nhi == 31 && nlo == 32) || (nam > 0);
            if (!flag) {
                float probs[8], mask[8];
#pragma unroll
                for (int i = 0; i < 8; ++i) {
                    int sel = logit[i] > val32 - EPSW;   // provably the exact top-32 set
                    mask[i]  = sel ? 1.f : 0.f;
                    probs[i] = sel ? 0.03125f : 0.f;
                }
                size_t row = (size_t)t * NEXP + e0;
                *(float4*)&out[row]                = make_float4(probs[0], probs[1], probs[2], probs[3]);
                *(float4*)&out[row + 4]            = make_float4(probs[4], probs[5], probs[6], probs[7]);
                *(float4*)&out[out_mask + row]     = make_float4(mask[0], mask[1], mask[2], mask[3]);
                *(float4*)&out[out_mask + row + 4] = make_float4(mask[4], mask[5], mask[6], mask[7]);
            }
        }
        if (eg == 0) flags_i[tl] = flag;
    }
    __syncthreads();

    // ---- exact pass for flagged rows (block-cooperative, f32) ----
    for (int tf = 0; tf < 64; ++tf) {
        if (flags_i[tf] == 0) continue;
        {
            float4 v = *(const float4*)&x[(size_t)(tbase + tf) * HID + tid * 4];
            *(float4*)&xrow[tid * 4] = v;
        }
        __syncthreads();
        const int e = tid & 63;
        const int q = tid >> 6;
        const float* wp = wn + (size_t)q * 256 * NEXP + e;
        const float* xr = xrow + q * 256;
        float dot = 0.f;
#pragma unroll 8
        for (int k2 = 0; k2 < 256; ++k2)
            dot = fmaf(xr[k2], wp[(size_t)k2 * NEXP], dot);
        part[q * 64 + e] = dot;
        __syncthreads();
        if (tid < 64) {
            const float sst = (ss_part[tf] + ss_part[64 + tf])
                            + (ss_part[128 + tf] + ss_part[192 + tf]);
            const float inv = 1.0f / fmaxf(sqrtf(sst), EPSF);
            const float lgv = ((part[e] + part[64 + e]) + (part[128 + e] + part[192 + e])) * inv;
            const float pr = lgv - thr_l[e];
            unsigned long long act = __ballot(pr > 0.f);
            float probs, mask;
            if (act) {
                float g = fmaxf(pr, 0.f);
                float mv = (pr > 0.f) ? g : -INFINITY;
#pragma unroll
                for (int d = 1; d < 64; d <<= 1) mv = fmaxf(mv, __shfl_xor(mv, d));
                float ex = (pr > 0.f) ? expf(g - mv) : 0.f;
                float s = ex;
#pragma unroll
                for (int d = 1; d < 64; d <<= 1) s += __shfl_xor(s, d);
                probs = ex / s;
                mask  = (pr > 0.f) ? 1.f : 0.f;
            } else {
                unsigned key = enc_key(lgv);
                unsigned cand = 0u;
                for (int bit = 31; bit >= 0; --bit) {
                    unsigned test = cand | (1u << bit);
                    int c = __popcll(__ballot(key >= test));
                    if (c >= 32) cand = test;
                }
                int need = 32 - __popcll(__ballot(key > cand));
                unsigned long long em = __ballot(key == cand);
                unsigned long long mlt = e ? (~0ull >> (64 - e)) : 0ull;
                int below = __popcll(em & mlt);
                int sel = (key > cand) || ((key == cand) && (below < need));
                probs = sel ? 0.03125f : 0.f;
                mask  = sel ? 1.f : 0.f;
            }
            size_t row = (size_t)(tbase + tf) * NEXP;
            out[row + e] = probs;
            out[out_mask + row + e] = mask;
        }
        __syncthreads();
    }
}

// ---------------- v10 (round-10 kernel, fallback) ----------------
__global__ __launch_bounds__(256) void gate_v10_kernel(const float* __restrict__ x,
                                                       const float* __restrict__ wn,
                                                       const float* __restrict__ prep,
                                                       float* __restrict__ out) {
    __shared__ __align__(16) float smem[8704];
    float* ss_part = smem + 8448;
    const int tid  = threadIdx.x;
    const int lane = tid & 63;
    const int wv   = tid >> 6;
    const int tg   = lane >> 3;
    const int eg   = lane & 7;
    const int e0   = eg * 8;
    const int tbase = blockIdx.x * 64;
    const int kbase = wv * 256;
    float* xsw = smem + wv * 2112;
    const float4* xq4 = (const float4*)(x + (size_t)(tbase + lane) * HID + kbase);
    float acc[8][8];
#pragma unroll
    for (int t = 0; t < 8; ++t)
#pragma unroll
        for (int e = 0; e < 8; ++e) acc[t][e] = 0.f;
    float ss = 0.f;
    {
        float4 f0 = xq4[0], f1 = xq4[1];
        const float4* wq4 = (const float4*)(wn + (size_t)kbase * NEXP) + lane * 2;
        float4 w0 = wq4[0], w1 = wq4[1];
        const float a[8] = { f0.x, f0.y, f0.z, f0.w, f1.x, f1.y, f1.z, f1.w };
#pragma unroll
        for (int i = 0; i < 8; ++i) { ss = fmaf(a[i], a[i], ss); xsw[i * 68 + lane] = a[i]; }
        *(float4*)&xsw[1088 + lane * 8]     = w0;
        *(float4*)&xsw[1088 + lane * 8 + 4] = w1;
    }
#define FMA8x8(XA, XB, WA, WB)                                              \
    do {                                                                    \
        const float xv_[8] = { XA.x, XA.y, XA.z, XA.w, XB.x, XB.y, XB.z, XB.w }; \
        const float wv_[8] = { WA.x, WA.y, WA.z, WA.w, WB.x, WB.y, WB.z, WB.w }; \
        _Pragma("unroll")                                                   \
        for (int t_ = 0; t_ < 8; ++t_)                                      \
            _Pragma("unroll")                                               \
            for (int e_ = 0; e_ < 8; ++e_)                                  \
                acc[t_][e_] = fmaf(xv_[t_], wv_[e_], acc[t_][e_]);          \
    } while (0)
#pragma unroll 1
    for (int c = 0; c < 32; ++c) {
        float4 sx0, sx1, sw0, sw1;
        if (c < 31) {
            sx0 = xq4[(c + 1) * 2];
            sx1 = xq4[(c + 1) * 2 + 1];
            const float4* wq4 = (const float4*)(wn + (size_t)(kbase + (c + 1) * 8) * NEXP) + lane * 2;
            sw0 = wq4[0]; sw1 = wq4[1];
        }
        const float* xb = xsw + (c & 1) * 544;
        const float* wb = xsw + 1088 + (c & 1) * 512;
#pragma unroll
        for (int k = 0; k < 8; ++k) {
            const float4 xa = *(const float4*)&xb[k * 68 + tg * 8];
            const float4 xc = *(const float4*)&xb[k * 68 + tg * 8 + 4];
            const float4 wa = *(const float4*)&wb[k * 64 + e0];
            const float4 wc = *(const float4*)&wb[k * 64 + e0 + 4];
            FMA8x8(xa, xc, wa, wc);
        }
        if (c < 31) {
            float* xn = xsw + ((c + 1) & 1) * 544;
            float* wl = xsw + 1088 + ((c + 1) & 1) * 512;
            const float a[8] = { sx0.x, sx0.y, sx0.z, sx0.w, sx1.x, sx1.y, sx1.z, sx1.w };
#pragma unroll
            for (int i = 0; i < 8; ++i) { ss = fmaf(a[i], a[i], ss); xn[i * 68 + lane] = a[i]; }
            *(float4*)&wl[lane * 8]     = sw0;
            *(float4*)&wl[lane * 8 + 4] = sw1;
        }
    }
#undef FMA8x8
    ss_part[wv * 64 + lane] = ss;
    __syncthreads();
    if (wv < 2) {
        float* reg = smem + wv * 4224;
#pragma unroll
        for (int j = 0; j < 8; ++j) {
            float* p = &reg[(tg * 8 + j) * 65 + e0];
            *(float4*)(p)     = make_float4(acc[j][0], acc[j][1], acc[j][2], acc[j][3]);
            *(float4*)(p + 4) = make_float4(acc[j][4], acc[j][5], acc[j][6], acc[j][7]);
        }
    }
    __syncthreads();
    if (wv >= 2) {
        float* reg = smem + (wv - 2) * 4224;
#pragma unroll
        for (int j = 0; j < 8; ++j) {
            float* p = &reg[(tg * 8 + j) * 65 + e0];
            float4 p0 = *(const float4*)(p);
            float4 p1 = *(const float4*)(p + 4);
            p0.x += acc[j][0]; p0.y += acc[j][1]; p0.z += acc[j][2]; p0.w += acc[j][3];
            p1.x += acc[j][4]; p1.y += acc[j][5]; p1.z += acc[j][6]; p1.w += acc[j][7];
            *(float4*)(p) = p0; *(float4*)(p + 4) = p1;
        }
    }
    __syncthreads();
    float thr[8];
#pragma unroll
    for (int i = 0; i < 8; ++i) thr[i] = prep[64 + e0 + i];
    const size_t out_pre  = (size_t)N_TOK * NEXP;
    const size_t out_mask = 2 * (size_t)N_TOK * NEXP;
    const float* regA = smem;
    const float* regB = smem + 4224;
#pragma unroll
    for (int j = 0; j < 2; ++j) {
        const int tl = wv * 16 + tg * 2 + j;
        const int t  = tbase + tl;
        const float sst = (ss_part[tl] + ss_part[64 + tl]) + (ss_part[128 + tl] + ss_part[192 + tl]);
        const float inv = 1.0f / fmaxf(sqrtf(sst), EPSF);
        float4 aA0 = *(const float4*)&regA[tl * 65 + e0];
        float4 aA1 = *(const float4*)&regA[tl * 65 + e0 + 4];
        float4 aB0 = *(const float4*)&regB[tl * 65 + e0];
        float4 aB1 = *(const float4*)&regB[tl * 65 + e0 + 4];
        float logit[8] = { (aA0.x + aB0.x) * inv, (aA0.y + aB0.y) * inv,
                           (aA0.z + aB0.z) * inv, (aA0.w + aB0.w) * inv,
                           (aA1.x + aB1.x) * inv, (aA1.y + aB1.y) * inv,
                           (aA1.z + aB1.z) * inv, (aA1.w + aB1.w) * inv };
        float pre[8], gated[8];
        int active[8];
        int myact = 0;
#pragma unroll
        for (int i = 0; i < 8; ++i) {
            pre[i]   = logit[i] - thr[i];
            gated[i] = fmaxf(pre[i], 0.f);
            active[i] = pre[i] > 0.f;
            myact += active[i];
        }
        int rowact = myact;
        rowact += __shfl_xor(rowact, 1, 8);
        rowact += __shfl_xor(rowact, 2, 8);
        rowact += __shfl_xor(rowact, 4, 8);
        float probs[8], mask[8];
        if (rowact > 0) {
            float m = -INFINITY;
#pragma unroll
            for (int i = 0; i < 8; ++i) m = fmaxf(m, active[i] ? gated[i] : -INFINITY);
            m = fmaxf(m, __shfl_xor(m, 1, 8));
            m = fmaxf(m, __shfl_xor(m, 2, 8));
            m = fmaxf(m, __shfl_xor(m, 4, 8));
            float s = 0.f;
#pragma unroll
            for (int i = 0; i < 8; ++i) { float ev = active[i] ? expf(gated[i] - m) : 0.f; probs[i] = ev; s += ev; }
            s += __shfl_xor(s, 1, 8);
            s += __shfl_xor(s, 2, 8);
            s += __shfl_xor(s, 4, 8);
            float rs = 1.0f / s;
#pragma unroll
            for (int i = 0; i < 8; ++i) { probs[i] *= rs; mask[i] = active[i] ? 1.f : 0.f; }
        } else {
            unsigned key[8];
#pragma unroll
            for (int i = 0; i < 8; ++i) key[i] = enc_key(logit[i]);
            unsigned cand = 0u;
            for (int bit = 31; bit >= 0; --bit) {
                unsigned test = cand | (1u << bit);
                int c = 0;
#pragma unroll
                for (int i = 0; i < 8; ++i) c += (key[i] >= test);
                c += __shfl_xor(c, 1, 8);
                c += __shfl_xor(c, 2, 8);
                c += __shfl_xor(c, 4, 8);
                if (c >= 32) cand = test;
            }
            int cgt = 0;
#pragma unroll
            for (int i = 0; i < 8; ++i) cgt += (key[i] > cand);
            cgt += __shfl_xor(cgt, 1, 8);
            cgt += __shfl_xor(cgt, 2, 8);
            cgt += __shfl_xor(cgt, 4, 8);
            int need_eq = 32 - cgt;
            int eqc = 0;
#pragma unroll
            for (int i = 0; i < 8; ++i) eqc += (key[i] == cand);
            int scan = eqc, tmp;
            tmp = __shfl_up(scan, 1, 8); if (eg >= 1) scan += tmp;
            tmp = __shfl_up(scan, 2, 8); if (eg >= 2) scan += tmp;
            tmp = __shfl_up(scan, 4, 8); if (eg >= 4) scan += tmp;
            int run = scan - eqc;
#pragma unroll
            for (int i = 0; i < 8; ++i) {
                int sel = (key[i] > cand) || ((key[i] == cand) && (run < need_eq));
                run += (key[i] == cand);
                mask[i]  = sel ? 1.f : 0.f;
                probs[i] = sel ? 0.03125f : 0.f;
            }
        }
        const size_t row = (size_t)t * NEXP + e0;
        *(float4*)&out[row]                = make_float4(probs[0], probs[1], probs[2], probs[3]);
        *(float4*)&out[row + 4]            = make_float4(probs[4], probs[5], probs[6], probs[7]);
        *(float4*)&out[out_pre + row]      = make_float4(pre[0], pre[1], pre[2], pre[3]);
        *(float4*)&out[out_pre + row + 4]  = make_float4(pre[4], pre[5], pre[6], pre[7]);
        *(float4*)&out[out_mask + row]     = make_float4(mask[0], mask[1], mask[2], mask[3]);
        *(float4*)&out[out_mask + row + 4] = make_float4(mask[4], mask[5], mask[6], mask[7]);
    }
}

extern "C" void kernel_launch(void* const* d_in, const int* in_sizes, int n_in,
                              void* d_out, int out_size, void* d_ws, size_t ws_size,
                              hipStream_t stream) {
    (void)in_sizes; (void)n_in; (void)out_size;
    const float* x     = (const float*)d_in[0];
    const float* sim   = (const float*)d_in[1];
    const float* gates = (const float*)d_in[2];
    float* out = (float*)d_out;
    float* ws  = (float*)d_ws;

    hipLaunchKernelGGL(prep_kernel, dim3(1), dim3(256), 0, stream, sim, gates, ws);

    const size_t need_v10 = 512 + (size_t)HID * NEXP * sizeof(float);
    const size_t need_v14 = need_v10 + 2 * (size_t)HID * NEXP * sizeof(short);
    if (ws_size >= need_v14) {
        float* wn = ws + 128;
        unsigned short* wbh = (unsigned short*)((char*)ws + 512 + (size_t)HID * NEXP * 4);
        unsigned short* wbl = wbh + (size_t)HID * NEXP;
        hipLaunchKernelGGL(prep2n_kernel, dim3(HID * NEXP / 256), dim3(256), 0, stream,
                           sim, ws, wn);
        hipLaunchKernelGGL(prep3_kernel, dim3(HID * NEXP / 256), dim3(256), 0, stream,
                           wn, wbh, wbl);
        hipLaunchKernelGGL(gate_v14_kernel, dim3(N_TOK / 64), dim3(256), 0, stream,
                           x, wn, wbh, wbl, ws, out);
    } else {
        float* wn = ws + 128;
        hipLaunchKernelGGL(prep2n_kernel, dim3(HID * NEXP / 256), dim3(256), 0, stream,
                           sim, ws, wn);
        hipLaunchKernelGGL(gate_v10_kernel, dim3(N_TOK / 64), dim3(256), 0, stream,
                           x, wn, ws, out);
    }
}

// Round 15
// 161.033 us; speedup vs baseline: 1.4436x; 1.1256x over previous
//
#include <hip/hip_runtime.h>
#include <math.h>

#define N_TOK   65536
#define HID     1024
#define NEXP    64
#define EPSF    1e-12f

__device__ __forceinline__ unsigned enc_key(float f) {
    unsigned u = __float_as_uint(f);
    return (u & 0x80000000u) ? ~u : (u | 0x80000000u);
}

// ---------------- prep: ws[0..63] = 1/||sim col||, ws[64..127] = sigmoid(gates)
__global__ __launch_bounds__(256) void prep_kernel(const float* __restrict__ sim,
                                                   const float* __restrict__ gates,
                                                   float* __restrict__ ws) {
    __shared__ float partial[4][64];
    int e = threadIdx.x & 63;
    int q = threadIdx.x >> 6;
    float s = 0.f;
    for (int h = q * 256; h < q * 256 + 256; ++h) {
        float v = sim[h * NEXP + e];
        s += v * v;
    }
    partial[q][e] = s;
    __syncthreads();
    if (threadIdx.x < 64) {
        float ss = partial[0][e] + partial[1][e] + partial[2][e] + partial[3][e];
        ws[e] = 1.0f / fmaxf(sqrtf(ss), EPSF);
        ws[64 + e] = 1.0f / (1.0f + expf(-gates[e]));
    }
}

// ---------------- prep2: normalized W f32: wn[k*64+e] = sim[k*64+e]*invcol[e]
__global__ __launch_bounds__(256) void prep2n_kernel(const float* __restrict__ sim,
                                                     const float* __restrict__ ws_ro,
                                                     float* __restrict__ wn) {
    int idx = blockIdx.x * 256 + threadIdx.x;
    wn[idx] = sim[idx] * ws_ro[idx & 63];
}

// ---------------- main kernel v10b: round-10 champion + W-tile pad 64->68.
// 256 thr = 4 waves, K-split by 4; chunk = 8 k double-buffered; W staged in
// per-wave LDS. v10's 2.29M bank conflicts traced to W staging ds_write_b128
// at lane*8 (16 lanes/bank-quad). [8][68] W rows spread writes across all 8
// bank-quads (inherent minimum) and make W reads conflict-free. Values and
// fmaf order bit-identical to v10.
__global__ __launch_bounds__(256) void gate_v10b_kernel(const float* __restrict__ x,
                                                        const float* __restrict__ wn,
                                                        const float* __restrict__ prep,
                                                        float* __restrict__ out) {
    // per-wave region (2176 floats): xs [2][8][68] at 0, W [2][8][68] at 1088.
    // overlay after GEMM: plane A [64][65] at 0, plane B at 4352.
    // ss_part[4][64] at 8704.
    __shared__ __align__(16) float smem[8960];
    float* ss_part = smem + 8704;

    const int tid  = threadIdx.x;
    const int lane = tid & 63;
    const int wv   = tid >> 6;            // k-quarter
    const int tg   = lane >> 3;
    const int eg   = lane & 7;
    const int e0   = eg * 8;
    const int tbase = blockIdx.x * 64;
    const int kbase = wv * 256;

    float* xsw = smem + wv * 2176;
    const int wst = (lane >> 3) * 68 + (lane & 7) * 8;   // W staging slot

    const float4* xq4 = (const float4*)(x + (size_t)(tbase + lane) * HID + kbase);

    float acc[8][8];
#pragma unroll
    for (int t = 0; t < 8; ++t)
#pragma unroll
        for (int e = 0; e < 8; ++e) acc[t][e] = 0.f;
    float ss = 0.f;

    // ---- prologue: stage chunk 0 (8 k of x + 2KB of W), fuse ss ----
    {
        float4 f0 = xq4[0], f1 = xq4[1];
        const float4* wq4 = (const float4*)(wn + (size_t)kbase * NEXP) + lane * 2;
        float4 w0 = wq4[0], w1 = wq4[1];
        const float a[8] = { f0.x, f0.y, f0.z, f0.w, f1.x, f1.y, f1.z, f1.w };
#pragma unroll
        for (int i = 0; i < 8; ++i) {
            ss = fmaf(a[i], a[i], ss);
            xsw[i * 68 + lane] = a[i];
        }
        *(float4*)&xsw[1088 + wst]     = w0;
        *(float4*)&xsw[1088 + wst + 4] = w1;
    }

#define FMA8x8(XA, XB, WA, WB)                                              \
    do {                                                                    \
        const float xv_[8] = { XA.x, XA.y, XA.z, XA.w, XB.x, XB.y, XB.z, XB.w }; \
        const float wv_[8] = { WA.x, WA.y, WA.z, WA.w, WB.x, WB.y, WB.z, WB.w }; \
        _Pragma("unroll")                                                   \
        for (int t_ = 0; t_ < 8; ++t_)                                      \
            _Pragma("unroll")                                               \
            for (int e_ = 0; e_ < 8; ++e_)                                  \
                acc[t_][e_] = fmaf(xv_[t_], wv_[e_], acc[t_][e_]);          \
    } while (0)

#pragma unroll 1
    for (int c = 0; c < 32; ++c) {
        float4 sx0, sx1, sw0, sw1;
        if (c < 31) {
            sx0 = xq4[(c + 1) * 2];
            sx1 = xq4[(c + 1) * 2 + 1];
            const float4* wq4 = (const float4*)(wn + (size_t)(kbase + (c + 1) * 8) * NEXP)
                              + lane * 2;
            sw0 = wq4[0]; sw1 = wq4[1];
        }

        const float* xb = xsw + (c & 1) * 544;
        const float* wb = xsw + 1088 + (c & 1) * 544;

#pragma unroll
        for (int k = 0; k < 8; ++k) {
            const float4 xa = *(const float4*)&xb[k * 68 + tg * 8];
            const float4 xc = *(const float4*)&xb[k * 68 + tg * 8 + 4];
            const float4 wa = *(const float4*)&wb[k * 68 + e0];
            const float4 wc = *(const float4*)&wb[k * 68 + e0 + 4];
            FMA8x8(xa, xc, wa, wc);
        }

        if (c < 31) {
            float* xn = xsw + ((c + 1) & 1) * 544;
            float* wl = xsw + 1088 + ((c + 1) & 1) * 544;
            const float a[8] = { sx0.x, sx0.y, sx0.z, sx0.w, sx1.x, sx1.y, sx1.z, sx1.w };
#pragma unroll
            for (int i = 0; i < 8; ++i) {
                ss = fmaf(a[i], a[i], ss);
                xn[i * 68 + lane] = a[i];
            }
            *(float4*)&wl[wst]     = sw0;
            *(float4*)&wl[wst + 4] = sw1;
        }
    }
#undef FMA8x8

    // ---- combine the four k-quarter partials via plane overlay ----
    ss_part[wv * 64 + lane] = ss;
    __syncthreads();

    if (wv < 2) {
        float* reg = smem + wv * 4352;
#pragma unroll
        for (int j = 0; j < 8; ++j) {
            float* p = &reg[(tg * 8 + j) * 65 + e0];
            *(float4*)(p)     = make_float4(acc[j][0], acc[j][1], acc[j][2], acc[j][3]);
            *(float4*)(p + 4) = make_float4(acc[j][4], acc[j][5], acc[j][6], acc[j][7]);
        }
    }
    __syncthreads();
    if (wv >= 2) {
        float* reg = smem + (wv - 2) * 4352;
#pragma unroll
        for (int j = 0; j < 8; ++j) {
            float* p = &reg[(tg * 8 + j) * 65 + e0];
            float4 p0 = *(const float4*)(p);
            float4 p1 = *(const float4*)(p + 4);
            p0.x += acc[j][0]; p0.y += acc[j][1]; p0.z += acc[j][2]; p0.w += acc[j][3];
            p1.x += acc[j][4]; p1.y += acc[j][5]; p1.z += acc[j][6]; p1.w += acc[j][7];
            *(float4*)(p)     = p0;
            *(float4*)(p + 4) = p1;
        }
    }
    __syncthreads();

    // ---- epilogue: wave w -> local tokens w*16 .. w*16+15 ----
    float thr[8];
#pragma unroll
    for (int i = 0; i < 8; ++i) thr[i] = prep[64 + e0 + i];

    const size_t out_pre  = (size_t)N_TOK * NEXP;
    const size_t out_mask = 2 * (size_t)N_TOK * NEXP;
    const float* regA = smem;
    const float* regB = smem + 4352;

#pragma unroll
    for (int j = 0; j < 2; ++j) {
        const int tl = wv * 16 + tg * 2 + j;
        const int t  = tbase + tl;
        const float sst = (ss_part[tl] + ss_part[64 + tl])
                        + (ss_part[128 + tl] + ss_part[192 + tl]);
        const float inv = 1.0f / fmaxf(sqrtf(sst), EPSF);

        float4 aA0 = *(const float4*)&regA[tl * 65 + e0];
        float4 aA1 = *(const float4*)&regA[tl * 65 + e0 + 4];
        float4 aB0 = *(const float4*)&regB[tl * 65 + e0];
        float4 aB1 = *(const float4*)&regB[tl * 65 + e0 + 4];
        float logit[8] = { (aA0.x + aB0.x) * inv, (aA0.y + aB0.y) * inv,
                           (aA0.z + aB0.z) * inv, (aA0.w + aB0.w) * inv,
                           (aA1.x + aB1.x) * inv, (aA1.y + aB1.y) * inv,
                           (aA1.z + aB1.z) * inv, (aA1.w + aB1.w) * inv };
        float pre[8], gated[8];
        int active[8];
        int myact = 0;
#pragma unroll
        for (int i = 0; i < 8; ++i) {
            pre[i]   = logit[i] - thr[i];
            gated[i] = fmaxf(pre[i], 0.f);
            active[i] = pre[i] > 0.f;
            myact += active[i];
        }
        int rowact = myact;
        rowact += __shfl_xor(rowact, 1, 8);
        rowact += __shfl_xor(rowact, 2, 8);
        rowact += __shfl_xor(rowact, 4, 8);

        float probs[8], mask[8];
        if (rowact > 0) {
            float m = -INFINITY;
#pragma unroll
            for (int i = 0; i < 8; ++i) m = fmaxf(m, active[i] ? gated[i] : -INFINITY);
            m = fmaxf(m, __shfl_xor(m, 1, 8));
            m = fmaxf(m, __shfl_xor(m, 2, 8));
            m = fmaxf(m, __shfl_xor(m, 4, 8));
            float s = 0.f;
#pragma unroll
            for (int i = 0; i < 8; ++i) {
                float ev = active[i] ? expf(gated[i] - m) : 0.f;
                probs[i] = ev; s += ev;
            }
            s += __shfl_xor(s, 1, 8);
            s += __shfl_xor(s, 2, 8);
            s += __shfl_xor(s, 4, 8);
            float rs = 1.0f / s;
#pragma unroll
            for (int i = 0; i < 8; ++i) {
                probs[i] *= rs;
                mask[i] = active[i] ? 1.f : 0.f;
            }
        } else {
            unsigned key[8];
#pragma unroll
            for (int i = 0; i < 8; ++i) key[i] = enc_key(logit[i]);
            unsigned cand = 0u;
            for (int bit = 31; bit >= 0; --bit) {
                unsigned test = cand | (1u << bit);
                int c = 0;
#pragma unroll
                for (int i = 0; i < 8; ++i) c += (key[i] >= test);
                c += __shfl_xor(c, 1, 8);
                c += __shfl_xor(c, 2, 8);
                c += __shfl_xor(c, 4, 8);
                if (c >= 32) cand = test;
            }
            int cgt = 0;
#pragma unroll
            for (int i = 0; i < 8; ++i) cgt += (key[i] > cand);
            cgt += __shfl_xor(cgt, 1, 8);
            cgt += __shfl_xor(cgt, 2, 8);
            cgt += __shfl_xor(cgt, 4, 8);
            int need_eq = 32 - cgt;

            int eqc = 0;
#pragma unroll
            for (int i = 0; i < 8; ++i) eqc += (key[i] == cand);
            int scan = eqc, tmp;
            tmp = __shfl_up(scan, 1, 8); if (eg >= 1) scan += tmp;
            tmp = __shfl_up(scan, 2, 8); if (eg >= 2) scan += tmp;
            tmp = __shfl_up(scan, 4, 8); if (eg >= 4) scan += tmp;
            int run = scan - eqc;
#pragma unroll
            for (int i = 0; i < 8; ++i) {
                int sel = (key[i] > cand) || ((key[i] == cand) && (run < need_eq));
                run += (key[i] == cand);
                mask[i]  = sel ? 1.f : 0.f;
                probs[i] = sel ? 0.03125f : 0.f;
            }
        }

        const size_t row = (size_t)t * NEXP + e0;
        *(float4*)&out[row]                = make_float4(probs[0], probs[1], probs[2], probs[3]);
        *(float4*)&out[row + 4]            = make_float4(probs[4], probs[5], probs[6], probs[7]);
        *(float4*)&out[out_pre + row]      = make_float4(pre[0], pre[1], pre[2], pre[3]);
        *(float4*)&out[out_pre + row + 4]  = make_float4(pre[4], pre[5], pre[6], pre[7]);
        *(float4*)&out[out_mask + row]     = make_float4(mask[0], mask[1], mask[2], mask[3]);
        *(float4*)&out[out_mask + row + 4] = make_float4(mask[4], mask[5], mask[6], mask[7]);
    }
}

// ---------------- fallback (round-1 kernel, used only if ws too small) ----
#define TOKB    128
#define KC      64
#define XPAD    65

__global__ __launch_bounds__(256) void gate_kernel_fb(const float* __restrict__ x,
                                                      const float* __restrict__ sim,
                                                      const float* __restrict__ prep,
                                                      float* __restrict__ out) {
    __shared__ float x_lds[TOKB][XPAD];
    __shared__ float w_lds[KC][NEXP];
    __shared__ float ss_lds[TOKB];
    __shared__ float invcol[NEXP];
    __shared__ float thr_s[NEXP];

    const int tid = threadIdx.x;
    const int base_t = blockIdx.x * TOKB;

    if (tid < NEXP) { invcol[tid] = prep[tid]; thr_s[tid] = prep[64 + tid]; }
    if (tid < TOKB) ss_lds[tid] = 0.f;

    const int g_e = tid & 7;
    const int g_t = tid >> 3;
    const int e0 = g_e * 8;
    const int t0 = g_t * 4;

    const int lt = tid >> 4;
    const int lk = (tid & 15) * 4;

    float acc[4][8];
#pragma unroll
    for (int j = 0; j < 4; ++j)
#pragma unroll
        for (int i = 0; i < 8; ++i) acc[j][i] = 0.f;

    for (int kc = 0; kc < HID; kc += KC) {
        __syncthreads();
#pragma unroll
        for (int it = 0; it < 4; ++it) {
            int flat4 = it * 256 + tid;
            int k = flat4 >> 4;
            int e = (flat4 & 15) * 4;
            float4 v = *(const float4*)&sim[(size_t)(kc + k) * NEXP + e];
            v.x *= invcol[e]; v.y *= invcol[e + 1]; v.z *= invcol[e + 2]; v.w *= invcol[e + 3];
            *(float4*)&w_lds[k][e] = v;
        }
#pragma unroll
        for (int it = 0; it < 8; ++it) {
            int t = it * 16 + lt;
            float4 v = *(const float4*)&x[(size_t)(base_t + t) * HID + kc + lk];
            x_lds[t][lk + 0] = v.x; x_lds[t][lk + 1] = v.y;
            x_lds[t][lk + 2] = v.z; x_lds[t][lk + 3] = v.w;
            float s4 = v.x * v.x + v.y * v.y + v.z * v.z + v.w * v.w;
            s4 += __shfl_xor(s4, 1, 16);
            s4 += __shfl_xor(s4, 2, 16);
            s4 += __shfl_xor(s4, 4, 16);
            s4 += __shfl_xor(s4, 8, 16);
            if ((tid & 15) == 0) ss_lds[t] += s4;
        }
        __syncthreads();
#pragma unroll 8
        for (int k = 0; k < KC; ++k) {
            float x0 = x_lds[t0 + 0][k];
            float x1 = x_lds[t0 + 1][k];
            float x2 = x_lds[t0 + 2][k];
            float x3 = x_lds[t0 + 3][k];
            float4 w0 = *(const float4*)&w_lds[k][e0];
            float4 w1 = *(const float4*)&w_lds[k][e0 + 4];
            float wv[8] = { w0.x, w0.y, w0.z, w0.w, w1.x, w1.y, w1.z, w1.w };
#pragma unroll
            for (int i = 0; i < 8; ++i) {
                acc[0][i] += x0 * wv[i];
                acc[1][i] += x1 * wv[i];
                acc[2][i] += x2 * wv[i];
                acc[3][i] += x3 * wv[i];
            }
        }
    }

    const size_t out_pre  = (size_t)N_TOK * NEXP;
    const size_t out_mask = 2 * (size_t)N_TOK * NEXP;

#pragma unroll
    for (int j = 0; j < 4; ++j) {
        int t = t0 + j;
        float inv = 1.0f / fmaxf(sqrtf(ss_lds[t]), EPSF);
        float logit[8], pre[8], gated[8];
        int active[8];
        int myact = 0;
#pragma unroll
        for (int i = 0; i < 8; ++i) {
            logit[i] = acc[j][i] * inv;
            pre[i]   = logit[i] - thr_s[e0 + i];
            gated[i] = fmaxf(pre[i], 0.f);
            active[i] = pre[i] > 0.f;
            myact += active[i];
        }
        int rowact = myact;
        rowact += __shfl_xor(rowact, 1, 8);
        rowact += __shfl_xor(rowact, 2, 8);
        rowact += __shfl_xor(rowact, 4, 8);

        float probs[8], mask[8];
        if (rowact > 0) {
            float m = -INFINITY;
#pragma unroll
            for (int i = 0; i < 8; ++i) m = fmaxf(m, active[i] ? gated[i] : -INFINITY);
            m = fmaxf(m, __shfl_xor(m, 1, 8));
            m = fmaxf(m, __shfl_xor(m, 2, 8));
            m = fmaxf(m, __shfl_xor(m, 4, 8));
            float s = 0.f;
#pragma unroll
            for (int i = 0; i < 8; ++i) {
                float ev = active[i] ? expf(gated[i] - m) : 0.f;
                probs[i] = ev; s += ev;
            }
            s += __shfl_xor(s, 1, 8);
            s += __shfl_xor(s, 2, 8);
            s += __shfl_xor(s, 4, 8);
            float rs = 1.0f / s;
#pragma unroll
            for (int i = 0; i < 8; ++i) {
                probs[i] *= rs;
                mask[i] = active[i] ? 1.f : 0.f;
            }
        } else {
            unsigned key[8];
#pragma unroll
            for (int i = 0; i < 8; ++i) key[i] = enc_key(logit[i]);
            unsigned cand = 0u;
            for (int bit = 31; bit >= 0; --bit) {
                unsigned test = cand | (1u << bit);
                int c = 0;
#pragma unroll
                for (int i = 0; i < 8; ++i) c += (key[i] >= test);
                c += __shfl_xor(c, 1, 8);
                c += __shfl_xor(c, 2, 8);
                c += __shfl_xor(c, 4, 8);
                if (c >= 32) cand = test;
            }
            int cgt = 0;
#pragma unroll
            for (int i = 0; i < 8; ++i) cgt += (key[i] > cand);
            cgt += __shfl_xor(cgt, 1, 8);
            cgt += __shfl_xor(cgt, 2, 8);
            cgt += __shfl_xor(cgt, 4, 8);
            int need_eq = 32 - cgt;

            int eqc = 0;
#pragma unroll
            for (int i = 0; i < 8; ++i) eqc += (key[i] == cand);
            int scan = eqc, tmp;
            tmp = __shfl_up(scan, 1, 8); if (g_e >= 1) scan += tmp;
            tmp = __shfl_up(scan, 2, 8); if (g_e >= 2) scan += tmp;
            tmp = __shfl_up(scan, 4, 8); if (g_e >= 4) scan += tmp;
            int run = scan - eqc;
#pragma unroll
            for (int i = 0; i < 8; ++i) {
                int sel = (key[i] > cand) || ((key[i] == cand) && (run < need_eq));
                run += (key[i] == cand);
                mask[i]  = sel ? 1.f : 0.f;
                probs[i] = sel ? 0.03125f : 0.f;
            }
        }

        size_t row = (size_t)(base_t + t) * NEXP + e0;
        *(float4*)&out[row]                = make_float4(probs[0], probs[1], probs[2], probs[3]);
        *(float4*)&out[row + 4]            = make_float4(probs[4], probs[5], probs[6], probs[7]);
        *(float4*)&out[out_pre + row]      = make_float4(pre[0], pre[1], pre[2], pre[3]);
        *(float4*)&out[out_pre + row + 4]  = make_float4(pre[4], pre[5], pre[6], pre[7]);
        *(float4*)&out[out_mask + row]     = make_float4(mask[0], mask[1], mask[2], mask[3]);
        *(float4*)&out[out_mask + row + 4] = make_float4(mask[4], mask[5], mask[6], mask[7]);
    }
}

extern "C" void kernel_launch(void* const* d_in, const int* in_sizes, int n_in,
                              void* d_out, int out_size, void* d_ws, size_t ws_size,
                              hipStream_t stream) {
    (void)in_sizes; (void)n_in; (void)out_size;
    const float* x     = (const float*)d_in[0];
    const float* sim   = (const float*)d_in[1];
    const float* gates = (const float*)d_in[2];
    float* out = (float*)d_out;
    float* ws  = (float*)d_ws;

    hipLaunchKernelGGL(prep_kernel, dim3(1), dim3(256), 0, stream, sim, gates, ws);

    const size_t need = 512 + (size_t)HID * NEXP * sizeof(float);   // prep + wn
    if (ws_size >= need) {
        float* wn = ws + 128;
        hipLaunchKernelGGL(prep2n_kernel, dim3(HID * NEXP / 256), dim3(256), 0, stream,
                           sim, ws, wn);
        hipLaunchKernelGGL(gate_v10b_kernel, dim3(N_TOK / 64), dim3(256), 0, stream,
                           x, wn, ws, out);
    } else {
        hipLaunchKernelGGL(gate_kernel_fb, dim3(N_TOK / TOKB), dim3(256), 0, stream,
                           x, sim, ws, out);
    }
}